// Round 1
// baseline (24702.734 us; speedup 1.0000x reference)
//
#include <hip/hip_runtime.h>
#include <hip/hip_bf16.h>
#include <math.h>

#define Hdim 512
#define Vv   100
#define V1n  101
#define Tt   20
#define Ln   2
#define Bb   1024
#define Mm   5
#define Kk   10
#define DFFn 2048

// ---------------- generic fp32 GEMM: C[M,N] = A[M,K] @ W[N,K]^T + bias, opt relu
#define BT 64
#define KT 16
__global__ __launch_bounds__(256)
void gemm_bias(const float* __restrict__ A, const float* __restrict__ W,
               const float* __restrict__ bias, float* __restrict__ C,
               int M, int N, int Kd, int relu)
{
    __shared__ float As[KT][BT + 1];
    __shared__ float Ws[KT][BT + 1];
    int tid = threadIdx.x;
    int tx = tid & 15, ty = tid >> 4;
    int bm = blockIdx.y * BT, bn = blockIdx.x * BT;
    float acc[4][4] = {};
    for (int k0 = 0; k0 < Kd; k0 += KT) {
#pragma unroll
        for (int r = 0; r < 4; ++r) {
            int idx = tid + r * 256;
            int mm = idx >> 4;      // 0..63
            int kk = idx & 15;
            As[kk][mm] = (bm + mm < M) ? A[(size_t)(bm + mm) * Kd + k0 + kk] : 0.f;
            Ws[kk][mm] = (bn + mm < N) ? W[(size_t)(bn + mm) * Kd + k0 + kk] : 0.f;
        }
        __syncthreads();
#pragma unroll
        for (int kk = 0; kk < KT; ++kk) {
            float a[4], w[4];
#pragma unroll
            for (int i = 0; i < 4; ++i) a[i] = As[kk][ty * 4 + i];
#pragma unroll
            for (int j = 0; j < 4; ++j) w[j] = Ws[kk][tx * 4 + j];
#pragma unroll
            for (int i = 0; i < 4; ++i)
#pragma unroll
                for (int j = 0; j < 4; ++j) acc[i][j] += a[i] * w[j];
        }
        __syncthreads();
    }
#pragma unroll
    for (int i = 0; i < 4; ++i) {
        int row = bm + ty * 4 + i;
        if (row >= M) continue;
#pragma unroll
        for (int j = 0; j < 4; ++j) {
            int col = bn + tx * 4 + j;
            if (col >= N) continue;
            float v = acc[i][j] + (bias ? bias[col] : 0.f);
            if (relu) v = fmaxf(v, 0.f);
            C[(size_t)row * N + col] = v;
        }
    }
}

// ---------------- src[b,h] = sum_m emb[(meanings[b,m]+m*K), h]
__global__ void src_kernel(const int* __restrict__ meanings,
                           const float* __restrict__ emb, float* __restrict__ src)
{
    int idx = blockIdx.x * 256 + threadIdx.x;   // B*H
    int b = idx >> 9, h = idx & 511;
    float s = 0.f;
#pragma unroll
    for (int m = 0; m < Mm; ++m) {
        int row = meanings[b * Mm + m] + m * Kk;
        s += emb[(size_t)row * Hdim + h];
    }
    src[idx] = s;
}

// ---------------- probs init: one-hot at V
__global__ void init_probs(float* __restrict__ probs)
{
    int idx = blockIdx.x * 256 + threadIdx.x;
    if (idx < Bb * V1n) probs[idx] = ((idx % V1n) == Vv) ? 1.f : 0.f;
}

// ---------------- x[b,h] = probs[b,:]@v2e_w[h,:] + v2e_b[h] + pe(pos,h)
__global__ void embed_kernel(const float* __restrict__ probs,
                             const float* __restrict__ v2e_w,
                             const float* __restrict__ v2e_b,
                             float* __restrict__ x, int pos)
{
    int idx = blockIdx.x * 256 + threadIdx.x;   // B*H
    int b = idx >> 9, h = idx & 511;
    const float* p = probs + (size_t)b * V1n;
    const float* w = v2e_w + (size_t)h * V1n;
    float s = 0.f;
    for (int v = 0; v < V1n; ++v) s += p[v] * w[v];
    s += v2e_b[h];
    int j2 = h & ~1;
    float div = expf(-(float)j2 * (logf(10000.f) / (float)Hdim));
    float ang = (float)pos * div;
    s += (h & 1) ? cosf(ang) : sinf(ang);
    x[idx] = s;
}

// ---------------- store K,V of current position into cache [t][b][h]
__global__ void kv_store(const float* __restrict__ qkv, float* __restrict__ kc,
                         float* __restrict__ vc, int pos)
{
    int idx = blockIdx.x * 256 + threadIdx.x;   // B*H
    int b = idx >> 9, h = idx & 511;
    kc[(size_t)pos * Bb * Hdim + idx] = qkv[(size_t)b * 3 * Hdim + Hdim + h];
    vc[(size_t)pos * Bb * Hdim + idx] = qkv[(size_t)b * 3 * Hdim + 2 * Hdim + h];
}

// ---------------- single-token attention against cache, one block per batch row
__global__ __launch_bounds__(256)
void attn_kernel(const float* __restrict__ qkv, const float* __restrict__ kc,
                 const float* __restrict__ vc, float* __restrict__ o, int step)
{
    int b = blockIdx.x;
    int tid = threadIdx.x;
    __shared__ float qs[Hdim];
    __shared__ float ss[Tt];
    const float* q = qkv + (size_t)b * 3 * Hdim;
    for (int h = tid; h < Hdim; h += 256) qs[h] = q[h];
    __syncthreads();
    int wave = tid >> 6, lane = tid & 63;
    for (int t = wave; t <= step; t += 4) {
        const float* k = kc + ((size_t)t * Bb + b) * Hdim;
        float p = 0.f;
        for (int h = lane; h < Hdim; h += 64) p += qs[h] * k[h];
        for (int off = 32; off; off >>= 1) p += __shfl_down(p, off);
        if (lane == 0) ss[t] = p * 0.044194173824159216f;  // 1/sqrt(512)
    }
    __syncthreads();
    float m = -1e30f;
    for (int t = 0; t <= step; ++t) m = fmaxf(m, ss[t]);
    float den = 0.f;
    for (int t = 0; t <= step; ++t) den += expf(ss[t] - m);
    float inv = 1.f / den;
    for (int h = tid; h < Hdim; h += 256) {
        float acc = 0.f;
        for (int t = 0; t <= step; ++t)
            acc += expf(ss[t] - m) * vc[((size_t)t * Bb + b) * Hdim + h];
        o[(size_t)b * Hdim + h] = acc * inv;
    }
}

// ---------------- x = LN(x + r) * g + b   (one block of 256 per row, H=512)
__global__ __launch_bounds__(256)
void ln_kernel(float* __restrict__ x, const float* __restrict__ r,
               const float* __restrict__ g, const float* __restrict__ bb)
{
    int b = blockIdx.x, tid = threadIdx.x;
    size_t base = (size_t)b * Hdim;
    float v0 = x[base + tid] + r[base + tid];
    float v1 = x[base + tid + 256] + r[base + tid + 256];
    float s = v0 + v1, s2 = v0 * v0 + v1 * v1;
    __shared__ float wsum[4], wsq[4];
    int lane = tid & 63, wv = tid >> 6;
    for (int off = 32; off; off >>= 1) {
        s += __shfl_down(s, off);
        s2 += __shfl_down(s2, off);
    }
    if (lane == 0) { wsum[wv] = s; wsq[wv] = s2; }
    __syncthreads();
    float S = wsum[0] + wsum[1] + wsum[2] + wsum[3];
    float S2 = wsq[0] + wsq[1] + wsq[2] + wsq[3];
    float mean = S * (1.f / Hdim);
    float var = S2 * (1.f / Hdim) - mean * mean;
    float inv = rsqrtf(var + 1e-5f);
    x[base + tid] = (v0 - mean) * inv * g[tid] + bb[tid];
    x[base + tid + 256] = (v1 - mean) * inv * g[tid + 256] + bb[tid + 256];
}

// ---------------- probs[b,:] = softmax(logits[b,:]), one wave per row
__global__ __launch_bounds__(64)
void softmax_kernel(const float* __restrict__ logits, float* __restrict__ probs)
{
    int b = blockIdx.x, lane = threadIdx.x;
    const float* lg = logits + (size_t)b * V1n;
    float v0 = (lane < V1n) ? lg[lane] : -1e30f;
    float v1 = (lane + 64 < V1n) ? lg[lane + 64] : -1e30f;
    float m = fmaxf(v0, v1);
    for (int off = 32; off; off >>= 1) m = fmaxf(m, __shfl_xor(m, off));
    float e0 = (lane < V1n) ? expf(v0 - m) : 0.f;
    float e1 = (lane + 64 < V1n) ? expf(v1 - m) : 0.f;
    float s = e0 + e1;
    for (int off = 32; off; off >>= 1) s += __shfl_xor(s, off);
    float inv = 1.f / s;
    if (lane < V1n) probs[(size_t)b * V1n + lane] = e0 * inv;
    if (lane + 64 < V1n) probs[(size_t)b * V1n + lane + 64] = e1 * inv;
}

extern "C" void kernel_launch(void* const* d_in, const int* in_sizes, int n_in,
                              void* d_out, int out_size, void* d_ws, size_t ws_size,
                              hipStream_t stream)
{
    const int*   meanings = (const int*)  d_in[0];
    const float* emb      = (const float*)d_in[1];
    const float* v2e_w    = (const float*)d_in[2];
    const float* v2e_b    = (const float*)d_in[3];
    const float* e2v_w    = (const float*)d_in[4];
    const float* e2v_b    = (const float*)d_in[5];
    const float* sa_in_w  = (const float*)d_in[6];
    const float* sa_in_b  = (const float*)d_in[7];
    const float* sa_out_w = (const float*)d_in[8];
    const float* sa_out_b = (const float*)d_in[9];
    const float* ca_in_w  = (const float*)d_in[10];
    const float* ca_in_b  = (const float*)d_in[11];
    const float* ca_out_w = (const float*)d_in[12];
    const float* ca_out_b = (const float*)d_in[13];
    const float* ff1_w    = (const float*)d_in[14];
    const float* ff1_b    = (const float*)d_in[15];
    const float* ff2_w    = (const float*)d_in[16];
    const float* ff2_b    = (const float*)d_in[17];
    const float* ln_g     = (const float*)d_in[18];
    const float* ln_b     = (const float*)d_in[19];
    float* out = (float*)d_out;

    // workspace layout (floats)
    float* ws = (float*)d_ws;
    size_t off = 0;
    float* probs    = ws + off; off += (size_t)Bb * V1n;
    float* x        = ws + off; off += (size_t)Bb * Hdim;
    float* src      = ws + off; off += (size_t)Bb * Hdim;
    float* vsrc     = ws + off; off += (size_t)Bb * Hdim;
    float* cross    = ws + off; off += (size_t)Ln * Bb * Hdim;
    float* qkv      = ws + off; off += (size_t)Bb * 3 * Hdim;
    float* o_buf    = ws + off; off += (size_t)Bb * Hdim;
    float* attn_out = ws + off; off += (size_t)Bb * Hdim;
    float* h1       = ws + off; off += (size_t)Bb * DFFn;
    float* ff_out   = ws + off; off += (size_t)Bb * Hdim;
    float* kcache   = ws + off; off += (size_t)Ln * Tt * Bb * Hdim;
    float* vcache   = ws + off; off += (size_t)Ln * Tt * Bb * Hdim;

    dim3 blk(256);
    int bh_blocks = (Bb * Hdim) / 256;

    // ---- precompute: src and per-layer cross-attention constant
    src_kernel<<<bh_blocks, blk, 0, stream>>>(meanings, emb, src);
    for (int l = 0; l < Ln; ++l) {
        const float* wv = ca_in_w + (size_t)l * 3 * Hdim * Hdim + (size_t)2 * Hdim * Hdim;
        const float* bv = ca_in_b + (size_t)l * 3 * Hdim + 2 * Hdim;
        gemm_bias<<<dim3(Hdim / BT, Bb / BT), blk, 0, stream>>>(
            src, wv, bv, vsrc, Bb, Hdim, Hdim, 0);
        gemm_bias<<<dim3(Hdim / BT, Bb / BT), blk, 0, stream>>>(
            vsrc, ca_out_w + (size_t)l * Hdim * Hdim, ca_out_b + (size_t)l * Hdim,
            cross + (size_t)l * Bb * Hdim, Bb, Hdim, Hdim, 0);
    }
    init_probs<<<(Bb * V1n + 255) / 256, blk, 0, stream>>>(probs);

    // ---- autoregressive loop, incremental decoding with KV cache
    for (int i = 0; i < Tt; ++i) {
        embed_kernel<<<bh_blocks, blk, 0, stream>>>(probs, v2e_w, v2e_b, x, i);
        for (int l = 0; l < Ln; ++l) {
            float* kc = kcache + (size_t)l * Tt * Bb * Hdim;
            float* vc = vcache + (size_t)l * Tt * Bb * Hdim;
            gemm_bias<<<dim3(3 * Hdim / BT, Bb / BT), blk, 0, stream>>>(
                x, sa_in_w + (size_t)l * 3 * Hdim * Hdim, sa_in_b + (size_t)l * 3 * Hdim,
                qkv, Bb, 3 * Hdim, Hdim, 0);
            kv_store<<<bh_blocks, blk, 0, stream>>>(qkv, kc, vc, i);
            attn_kernel<<<Bb, blk, 0, stream>>>(qkv, kc, vc, o_buf, i);
            gemm_bias<<<dim3(Hdim / BT, Bb / BT), blk, 0, stream>>>(
                o_buf, sa_out_w + (size_t)l * Hdim * Hdim, sa_out_b + (size_t)l * Hdim,
                attn_out, Bb, Hdim, Hdim, 0);
            ln_kernel<<<Bb, blk, 0, stream>>>(x, attn_out,
                ln_g + (size_t)(l * 3 + 0) * Hdim, ln_b + (size_t)(l * 3 + 0) * Hdim);
            ln_kernel<<<Bb, blk, 0, stream>>>(x, cross + (size_t)l * Bb * Hdim,
                ln_g + (size_t)(l * 3 + 1) * Hdim, ln_b + (size_t)(l * 3 + 1) * Hdim);
            gemm_bias<<<dim3(DFFn / BT, Bb / BT), blk, 0, stream>>>(
                x, ff1_w + (size_t)l * DFFn * Hdim, ff1_b + (size_t)l * DFFn,
                h1, Bb, DFFn, Hdim, 1);
            gemm_bias<<<dim3(Hdim / BT, Bb / BT), blk, 0, stream>>>(
                h1, ff2_w + (size_t)l * Hdim * DFFn, ff2_b + (size_t)l * Hdim,
                ff_out, Bb, Hdim, DFFn, 0);
            ln_kernel<<<Bb, blk, 0, stream>>>(x, ff_out,
                ln_g + (size_t)(l * 3 + 2) * Hdim, ln_b + (size_t)(l * 3 + 2) * Hdim);
        }
        float* logits = out + (size_t)i * Bb * V1n;
        gemm_bias<<<dim3((V1n + BT - 1) / BT, Bb / BT), blk, 0, stream>>>(
            x, e2v_w, e2v_b, logits, Bb, V1n, Hdim, 0);
        softmax_kernel<<<Bb, dim3(64), 0, stream>>>(logits, probs);
    }
}

// Round 2
// 8143.464 us; speedup vs baseline: 3.0334x; 3.0334x over previous
//
#include <hip/hip_runtime.h>
#include <hip/hip_bf16.h>
#include <math.h>

#define Hdim 512
#define Vv   100
#define V1n  101
#define Tt   20
#define Ln   2
#define Bb   1024
#define Mm   5
#define Kk   10
#define DFFn 2048

// ============================================================================
// fp32 GEMM: C[M,N] = A[M,K] @ W[N,K]^T (+bias)
// 64x64 tile, BK=32, 256 threads, 4x4 microtile, double-buffered LDS,
// float4 global loads, b128 LDS fragment reads.
// EPI: 0 = plain (+bias if z==0), 1 = relu(+bias), 2 = QKV split (q/kcache/vcache)
// split-K via blockIdx.z: chunk z covers K range [z*kcount, (z+1)*kcount),
// writes to C + z*M*N (separate partial buffers -> deterministic).
// ============================================================================
template<int EPI>
__global__ __launch_bounds__(256) void gemm64(
    const float* __restrict__ A, const float* __restrict__ W,
    const float* __restrict__ bias, float* __restrict__ C,
    int M, int N, int Kd, int kcount,
    float* __restrict__ kc, float* __restrict__ vc, int pos)
{
    __shared__ float As[2][32][68];
    __shared__ float Ws[2][32][68];
    const int tid = threadIdx.x;
    const int tx = tid & 15, ty = tid >> 4;
    const int bm = blockIdx.y * 64, bn = blockIdx.x * 64;
    const int koff = blockIdx.z * kcount;
    const int r0 = tid >> 3, k4 = tid & 7;   // 32 rows x 8 float4-per-row mapping
    const float* Ab = A + (size_t)bm * Kd + koff + k4 * 4;
    const float* Wb = W + (size_t)bn * Kd + koff + k4 * 4;
    const int nk = kcount >> 5;

    float4 la0, la1, lw0, lw1;

    float acc[4][4] = {};

    // prologue: fetch tile 0
    {
        const float* ap = Ab;
        const float* wp = Wb;
        la0 = *(const float4*)(ap + (size_t)r0 * Kd);
        la1 = *(const float4*)(ap + (size_t)(r0 + 32) * Kd);
        lw0 = *(const float4*)(wp + (size_t)r0 * Kd);
        lw1 = *(const float4*)(wp + (size_t)(r0 + 32) * Kd);
        int kb = k4 * 4;
        As[0][kb+0][r0] = la0.x; As[0][kb+1][r0] = la0.y; As[0][kb+2][r0] = la0.z; As[0][kb+3][r0] = la0.w;
        As[0][kb+0][r0+32] = la1.x; As[0][kb+1][r0+32] = la1.y; As[0][kb+2][r0+32] = la1.z; As[0][kb+3][r0+32] = la1.w;
        Ws[0][kb+0][r0] = lw0.x; Ws[0][kb+1][r0] = lw0.y; Ws[0][kb+2][r0] = lw0.z; Ws[0][kb+3][r0] = lw0.w;
        Ws[0][kb+0][r0+32] = lw1.x; Ws[0][kb+1][r0+32] = lw1.y; Ws[0][kb+2][r0+32] = lw1.z; Ws[0][kb+3][r0+32] = lw1.w;
    }
    __syncthreads();

    int buf = 0;
    for (int t = 0; t < nk; ++t) {
        if (t + 1 < nk) {
            const float* ap = Ab + (t + 1) * 32;
            const float* wp = Wb + (t + 1) * 32;
            la0 = *(const float4*)(ap + (size_t)r0 * Kd);
            la1 = *(const float4*)(ap + (size_t)(r0 + 32) * Kd);
            lw0 = *(const float4*)(wp + (size_t)r0 * Kd);
            lw1 = *(const float4*)(wp + (size_t)(r0 + 32) * Kd);
        }
#pragma unroll
        for (int kk = 0; kk < 32; ++kk) {
            float4 av = *(const float4*)&As[buf][kk][ty * 4];
            float4 wv = *(const float4*)&Ws[buf][kk][tx * 4];
            acc[0][0] += av.x * wv.x; acc[0][1] += av.x * wv.y; acc[0][2] += av.x * wv.z; acc[0][3] += av.x * wv.w;
            acc[1][0] += av.y * wv.x; acc[1][1] += av.y * wv.y; acc[1][2] += av.y * wv.z; acc[1][3] += av.y * wv.w;
            acc[2][0] += av.z * wv.x; acc[2][1] += av.z * wv.y; acc[2][2] += av.z * wv.z; acc[2][3] += av.z * wv.w;
            acc[3][0] += av.w * wv.x; acc[3][1] += av.w * wv.y; acc[3][2] += av.w * wv.z; acc[3][3] += av.w * wv.w;
        }
        if (t + 1 < nk) {
            int nb = buf ^ 1, kb = k4 * 4;
            As[nb][kb+0][r0] = la0.x; As[nb][kb+1][r0] = la0.y; As[nb][kb+2][r0] = la0.z; As[nb][kb+3][r0] = la0.w;
            As[nb][kb+0][r0+32] = la1.x; As[nb][kb+1][r0+32] = la1.y; As[nb][kb+2][r0+32] = la1.z; As[nb][kb+3][r0+32] = la1.w;
            Ws[nb][kb+0][r0] = lw0.x; Ws[nb][kb+1][r0] = lw0.y; Ws[nb][kb+2][r0] = lw0.z; Ws[nb][kb+3][r0] = lw0.w;
            Ws[nb][kb+0][r0+32] = lw1.x; Ws[nb][kb+1][r0+32] = lw1.y; Ws[nb][kb+2][r0+32] = lw1.z; Ws[nb][kb+3][r0+32] = lw1.w;
        }
        __syncthreads();
        buf ^= 1;
    }

    if (EPI == 2) {
        // QKV: cols [0,512)->q (C as [B][512]), [512,1024)->kcache, [1024,1536)->vcache
        int seg = bn >> 9;
        int cl = (bn & 511) + tx * 4;
        float* dst;
        if (seg == 0)      dst = C;
        else if (seg == 1) dst = kc + (size_t)pos * M * Hdim;
        else               dst = vc + (size_t)pos * M * Hdim;
#pragma unroll
        for (int i = 0; i < 4; ++i) {
            int row = bm + ty * 4 + i;
            float4 o;
            o.x = acc[i][0] + bias[bn + tx * 4 + 0];
            o.y = acc[i][1] + bias[bn + tx * 4 + 1];
            o.z = acc[i][2] + bias[bn + tx * 4 + 2];
            o.w = acc[i][3] + bias[bn + tx * 4 + 3];
            *(float4*)(dst + (size_t)row * Hdim + cl) = o;
        }
    } else {
        const float* bp = (bias && blockIdx.z == 0) ? bias : nullptr;
        float* Cz = C + (size_t)blockIdx.z * M * N;
#pragma unroll
        for (int i = 0; i < 4; ++i) {
            int row = bm + ty * 4 + i;
            float4 o;
            o.x = acc[i][0] + (bp ? bp[bn + tx * 4 + 0] : 0.f);
            o.y = acc[i][1] + (bp ? bp[bn + tx * 4 + 1] : 0.f);
            o.z = acc[i][2] + (bp ? bp[bn + tx * 4 + 2] : 0.f);
            o.w = acc[i][3] + (bp ? bp[bn + tx * 4 + 3] : 0.f);
            if (EPI == 1) {
                o.x = fmaxf(o.x, 0.f); o.y = fmaxf(o.y, 0.f);
                o.z = fmaxf(o.z, 0.f); o.w = fmaxf(o.w, 0.f);
            }
            *(float4*)(Cz + (size_t)row * N + bn + tx * 4) = o;
        }
    }
}

// ---------------- src[b,h] = sum_m emb[(meanings[b,m]+m*K), h]
__global__ void src_kernel(const int* __restrict__ meanings,
                           const float* __restrict__ emb, float* __restrict__ src)
{
    int idx = blockIdx.x * 256 + threadIdx.x;   // B*H
    int b = idx >> 9, h = idx & 511;
    float s = 0.f;
#pragma unroll
    for (int m = 0; m < Mm; ++m) {
        int row = meanings[b * Mm + m] + m * Kk;
        s += emb[(size_t)row * Hdim + h];
    }
    src[idx] = s;
}

// ---------------- x0[b,h] = v2e_w[h,V] + v2e_b[h] + pe(0,h)
__global__ void init_x(const float* __restrict__ v2e_w, const float* __restrict__ v2e_b,
                       float* __restrict__ x)
{
    int idx = blockIdx.x * 256 + threadIdx.x;
    int h = idx & 511;
    x[idx] = v2e_w[(size_t)h * V1n + Vv] + v2e_b[h] + ((h & 1) ? 1.f : 0.f);
}

// ---------------- single-token attention against cache
__global__ __launch_bounds__(256)
void attn_kernel(const float* __restrict__ q, const float* __restrict__ kc,
                 const float* __restrict__ vc, float* __restrict__ o, int step)
{
    __shared__ float qs[Hdim];
    __shared__ float ssm[32];
    __shared__ float wts[32];
    int b = blockIdx.x, tid = threadIdx.x, lane = tid & 63, wv = tid >> 6;
    qs[tid] = q[(size_t)b * Hdim + tid];
    qs[tid + 256] = q[(size_t)b * Hdim + tid + 256];
    __syncthreads();
    const float4* q4 = (const float4*)qs;
    for (int t = wv; t <= step; t += 4) {
        const float4* k4 = (const float4*)(kc + ((size_t)t * Bb + b) * Hdim);
        float4 qa = q4[lane], ka = k4[lane];
        float4 qb = q4[lane + 64], kb = k4[lane + 64];
        float p = qa.x*ka.x + qa.y*ka.y + qa.z*ka.z + qa.w*ka.w
                + qb.x*kb.x + qb.y*kb.y + qb.z*kb.z + qb.w*kb.w;
        for (int off = 32; off; off >>= 1) p += __shfl_down(p, off);
        if (!lane) ssm[t] = p * 0.044194173824159216f;
    }
    __syncthreads();
    float m = -1e30f;
    for (int t = 0; t <= step; ++t) m = fmaxf(m, ssm[t]);
    float den = 0.f;
    for (int t = 0; t <= step; ++t) den += expf(ssm[t] - m);
    if (tid <= step) wts[tid] = expf(ssm[tid] - m) / den;
    __syncthreads();
    float2 acc = make_float2(0.f, 0.f);
    for (int t = 0; t <= step; ++t) {
        float2 vv = *(const float2*)(vc + ((size_t)t * Bb + b) * Hdim + tid * 2);
        float w = wts[t];
        acc.x += w * vv.x; acc.y += w * vv.y;
    }
    *(float2*)(o + (size_t)b * Hdim + tid * 2) = acc;
}

// ---------------- block-row LN stats helper (256 thr, 512 elems)
__device__ __forceinline__ float2 rowstats(float v0, float v1, float* sh)
{
    __syncthreads();   // protect sh reuse across calls
    float s = v0 + v1, s2 = v0 * v0 + v1 * v1;
    int lane = threadIdx.x & 63, wv = threadIdx.x >> 6;
    for (int off = 32; off; off >>= 1) {
        s += __shfl_down(s, off);
        s2 += __shfl_down(s2, off);
    }
    if (!lane) { sh[wv] = s; sh[wv + 4] = s2; }
    __syncthreads();
    float S = sh[0] + sh[1] + sh[2] + sh[3];
    float S2 = sh[4] + sh[5] + sh[6] + sh[7];
    float mean = S * (1.f / Hdim);
    float var = S2 * (1.f / Hdim) - mean * mean;
    return make_float2(mean, rsqrtf(var + 1e-5f));
}

// ---------------- x = LN2( LN1(x + r0 + r1)*g0+b0 + cross )*g1+b1
__global__ __launch_bounds__(256)
void ln12_kernel(float* __restrict__ x, const float* __restrict__ r0,
                 const float* __restrict__ r1, const float* __restrict__ cross,
                 const float* __restrict__ g0, const float* __restrict__ b0,
                 const float* __restrict__ g1, const float* __restrict__ b1)
{
    __shared__ float sh[8];
    size_t base = (size_t)blockIdx.x * Hdim;
    int tid = threadIdx.x;
    float v0 = x[base + tid] + r0[base + tid] + r1[base + tid];
    float v1 = x[base + tid + 256] + r0[base + tid + 256] + r1[base + tid + 256];
    float2 st = rowstats(v0, v1, sh);
    float y0 = (v0 - st.x) * st.y * g0[tid] + b0[tid] + cross[base + tid];
    float y1 = (v1 - st.x) * st.y * g0[tid + 256] + b0[tid + 256] + cross[base + tid + 256];
    float2 st2 = rowstats(y0, y1, sh);
    x[base + tid] = (y0 - st2.x) * st2.y * g1[tid] + b1[tid];
    x[base + tid + 256] = (y1 - st2.x) * st2.y * g1[tid + 256] + b1[tid + 256];
}

// ---------------- x = LN(x + r0 + r1)*g+b
__global__ __launch_bounds__(256)
void ln3_kernel(float* __restrict__ x, const float* __restrict__ r0,
                const float* __restrict__ r1,
                const float* __restrict__ g, const float* __restrict__ b)
{
    __shared__ float sh[8];
    size_t base = (size_t)blockIdx.x * Hdim;
    int tid = threadIdx.x;
    float v0 = x[base + tid] + r0[base + tid] + r1[base + tid];
    float v1 = x[base + tid + 256] + r0[base + tid + 256] + r1[base + tid + 256];
    float2 st = rowstats(v0, v1, sh);
    x[base + tid] = (v0 - st.x) * st.y * g[tid] + b[tid];
    x[base + tid + 256] = (v1 - st.x) * st.y * g[tid + 256] + b[tid + 256];
}

// ---------------- per-row: logits = x @ e2v_w^T + e2v_b -> out;
//                  probs = softmax(logits); x <- probs @ v2e_w^T + v2e_b + pe(pos_next)
__global__ __launch_bounds__(256)
void finish_step(const float* __restrict__ e2v_w, const float* __restrict__ e2v_b,
                 const float* __restrict__ v2e_w, const float* __restrict__ v2e_b,
                 float* __restrict__ out_logits, float* __restrict__ x, int pos_next)
{
    __shared__ float xs[Hdim];
    __shared__ float ls[104];
    int b = blockIdx.x, tid = threadIdx.x, lane = tid & 63, wv = tid >> 6;
    xs[tid] = x[(size_t)b * Hdim + tid];
    xs[tid + 256] = x[(size_t)b * Hdim + tid + 256];
    __syncthreads();
    const float4* x4 = (const float4*)xs;
    for (int v = wv; v < V1n; v += 4) {
        const float4* w4 = (const float4*)(e2v_w + (size_t)v * Hdim);
        float4 xa = x4[lane], wa = w4[lane];
        float4 xb = x4[lane + 64], wb = w4[lane + 64];
        float p = xa.x*wa.x + xa.y*wa.y + xa.z*wa.z + xa.w*wa.w
                + xb.x*wb.x + xb.y*wb.y + xb.z*wb.z + xb.w*wb.w;
        for (int off = 32; off; off >>= 1) p += __shfl_down(p, off);
        if (!lane) ls[v] = p + e2v_b[v];
    }
    __syncthreads();
    if (tid < V1n) out_logits[(size_t)b * V1n + tid] = ls[tid];
    if (wv == 0) {
        float a0 = (lane < V1n) ? ls[lane] : -1e30f;
        float a1 = (lane + 64 < V1n) ? ls[lane + 64] : -1e30f;
        float mm = fmaxf(a0, a1);
        for (int off = 32; off; off >>= 1) mm = fmaxf(mm, __shfl_xor(mm, off));
        float e0 = (lane < V1n) ? expf(a0 - mm) : 0.f;
        float e1 = (lane + 64 < V1n) ? expf(a1 - mm) : 0.f;
        float ssum = e0 + e1;
        for (int off = 32; off; off >>= 1) ssum += __shfl_xor(ssum, off);
        float inv = 1.f / ssum;
        if (lane < V1n) ls[lane] = e0 * inv;
        if (lane + 64 < V1n) ls[lane + 64] = e1 * inv;
    }
    __syncthreads();
    for (int h = tid; h < Hdim; h += 256) {
        const float* wr = v2e_w + (size_t)h * V1n;
        float s = v2e_b[h];
        for (int v = 0; v < V1n; ++v) s += ls[v] * wr[v];
        int j2 = h & ~1;
        float div = expf(-(float)j2 * (logf(10000.f) / (float)Hdim));
        float ang = (float)pos_next * div;
        s += (h & 1) ? cosf(ang) : sinf(ang);
        x[(size_t)b * Hdim + h] = s;
    }
}

extern "C" void kernel_launch(void* const* d_in, const int* in_sizes, int n_in,
                              void* d_out, int out_size, void* d_ws, size_t ws_size,
                              hipStream_t stream)
{
    const int*   meanings = (const int*)  d_in[0];
    const float* emb      = (const float*)d_in[1];
    const float* v2e_w    = (const float*)d_in[2];
    const float* v2e_b    = (const float*)d_in[3];
    const float* e2v_w    = (const float*)d_in[4];
    const float* e2v_b    = (const float*)d_in[5];
    const float* sa_in_w  = (const float*)d_in[6];
    const float* sa_in_b  = (const float*)d_in[7];
    const float* sa_out_w = (const float*)d_in[8];
    const float* sa_out_b = (const float*)d_in[9];
    const float* ca_in_w  = (const float*)d_in[10];
    const float* ca_in_b  = (const float*)d_in[11];
    const float* ca_out_w = (const float*)d_in[12];
    const float* ca_out_b = (const float*)d_in[13];
    const float* ff1_w    = (const float*)d_in[14];
    const float* ff1_b    = (const float*)d_in[15];
    const float* ff2_w    = (const float*)d_in[16];
    const float* ff2_b    = (const float*)d_in[17];
    const float* ln_g     = (const float*)d_in[18];
    const float* ln_b     = (const float*)d_in[19];
    float* out = (float*)d_out;

    const size_t BH = (size_t)Bb * Hdim;
    float* ws = (float*)d_ws;
    size_t off = 0;
    float* x      = ws + off; off += BH;
    float* cross  = ws + off; off += Ln * BH;
    float* qbuf   = ws + off; off += BH;
    float* obuf   = ws + off; off += BH;
    float* p01    = ws + off; off += 2 * BH;          // out-proj split-K partials
    float* h1     = ws + off; off += (size_t)Bb * DFFn;
    float* f01    = ws + off; off += 2 * BH;          // FF2 split-K partials
    float* kcache = ws + off; off += (size_t)Ln * Tt * BH;
    float* vcache = ws + off; off += (size_t)Ln * Tt * BH;
    float* srcb   = h1;        // alias: setup only
    float* vsrcb  = obuf;      // alias: setup only

    dim3 blk(256);

    // ---- setup: src and per-layer cross-attention constant (S=1 shortcut)
    src_kernel<<<dim3(BH / 256), blk, 0, stream>>>(meanings, emb, srcb);
    for (int l = 0; l < Ln; ++l) {
        const float* wv = ca_in_w + (size_t)l * 3 * Hdim * Hdim + (size_t)2 * Hdim * Hdim;
        const float* bv = ca_in_b + (size_t)l * 3 * Hdim + 2 * Hdim;
        gemm64<0><<<dim3(Hdim / 64, Bb / 64, 1), blk, 0, stream>>>(
            srcb, wv, bv, vsrcb, Bb, Hdim, Hdim, Hdim, nullptr, nullptr, 0);
        gemm64<0><<<dim3(Hdim / 64, Bb / 64, 1), blk, 0, stream>>>(
            vsrcb, ca_out_w + (size_t)l * Hdim * Hdim, ca_out_b + (size_t)l * Hdim,
            cross + (size_t)l * BH, Bb, Hdim, Hdim, Hdim, nullptr, nullptr, 0);
    }
    init_x<<<dim3(BH / 256), blk, 0, stream>>>(v2e_w, v2e_b, x);

    // ---- autoregressive loop
    for (int i = 0; i < Tt; ++i) {
        for (int l = 0; l < Ln; ++l) {
            float* kc = kcache + (size_t)l * Tt * BH;
            float* vc = vcache + (size_t)l * Tt * BH;
            // QKV projection, epilogue scatters q/k/v
            gemm64<2><<<dim3(3 * Hdim / 64, Bb / 64, 1), blk, 0, stream>>>(
                x, sa_in_w + (size_t)l * 3 * Hdim * Hdim,
                sa_in_b + (size_t)l * 3 * Hdim, qbuf,
                Bb, 3 * Hdim, Hdim, Hdim, kc, vc, i);
            attn_kernel<<<dim3(Bb), blk, 0, stream>>>(qbuf, kc, vc, obuf, i);
            // attention out-proj, split-K x2
            gemm64<0><<<dim3(Hdim / 64, Bb / 64, 2), blk, 0, stream>>>(
                obuf, sa_out_w + (size_t)l * Hdim * Hdim,
                sa_out_b + (size_t)l * Hdim, p01,
                Bb, Hdim, Hdim, Hdim / 2, nullptr, nullptr, 0);
            ln12_kernel<<<dim3(Bb), blk, 0, stream>>>(
                x, p01, p01 + BH, cross + (size_t)l * BH,
                ln_g + (size_t)(l * 3 + 0) * Hdim, ln_b + (size_t)(l * 3 + 0) * Hdim,
                ln_g + (size_t)(l * 3 + 1) * Hdim, ln_b + (size_t)(l * 3 + 1) * Hdim);
            // FF1 (relu)
            gemm64<1><<<dim3(DFFn / 64, Bb / 64, 1), blk, 0, stream>>>(
                x, ff1_w + (size_t)l * DFFn * Hdim, ff1_b + (size_t)l * DFFn,
                h1, Bb, DFFn, Hdim, Hdim, nullptr, nullptr, 0);
            // FF2, split-K x2 (K=2048)
            gemm64<0><<<dim3(Hdim / 64, Bb / 64, 2), blk, 0, stream>>>(
                h1, ff2_w + (size_t)l * Hdim * DFFn, ff2_b + (size_t)l * Hdim,
                f01, Bb, Hdim, DFFn, DFFn / 2, nullptr, nullptr, 0);
            ln3_kernel<<<dim3(Bb), blk, 0, stream>>>(
                x, f01, f01 + BH,
                ln_g + (size_t)(l * 3 + 2) * Hdim, ln_b + (size_t)(l * 3 + 2) * Hdim);
        }
        finish_step<<<dim3(Bb), blk, 0, stream>>>(
            e2v_w, e2v_b, v2e_w, v2e_b,
            out + (size_t)i * Bb * V1n, x, i + 1);
    }
}

// Round 4
// 5358.985 us; speedup vs baseline: 4.6096x; 1.5196x over previous
//
#include <hip/hip_runtime.h>
#include <hip/hip_bf16.h>
#include <math.h>

#define Hdim 512
#define Vv   100
#define V1n  101
#define Tt   20
#define Ln   2
#define Bb   1024
#define Mm   5
#define Kk   10
#define DFFn 2048

typedef unsigned short u16;
typedef __attribute__((ext_vector_type(8))) short s16x8;   // 8 bf16 = 4 VGPR MFMA frag
typedef __attribute__((ext_vector_type(4))) float f32x4;   // 16x16 MFMA acc

static const size_t BH = (size_t)Bb * Hdim;

// ---- fp32 -> bf16 (RNE) and 3-way split: v ~= s0 + s1 + s2 (residual ~2^-26 rel)
__device__ __forceinline__ u16 f2bf(float f) {
    unsigned u = __float_as_uint(f);
    return (u16)((u + 0x7FFFu + ((u >> 16) & 1u)) >> 16);
}
__device__ __forceinline__ float bf2f(u16 b) { return __uint_as_float(((unsigned)b) << 16); }
__device__ __forceinline__ void split3(float v, u16* s) {
    u16 a = f2bf(v); float f0 = bf2f(a);
    float r = v - f0;
    u16 b = f2bf(r); float f1 = bf2f(b);
    s[0] = a; s[1] = b; s[2] = f2bf(r - f1);
}

// ============================================================================
// Split-3 bf16 MFMA GEMM: C[1024][N] = A[1024][K] @ W[N][K]^T
// mfma_f32_16x16x32_bf16 (HW-verified layout m89/m91):
//   A frag: lane holds A[row=lane&15][k=(lane>>4)*8 + j]
//   B frag: lane holds W[col=lane&15][k=(lane>>4)*8 + j]   (W row-major = B^T)
//   C/D   : col=lane&15, row=(lane>>4)*4 + reg
// Tile 128x64, BK=32, 256 thr = 4 waves; wave w owns rows [32w,32w+32).
// LDS in fragment order (all b128 ops). 6-term split product -> ~fp32 accuracy.
// EPI: 0 = fp32 partial -> C + z*1024*N
//      1 = bias+relu -> split3 planes Csp (+p*strC)
//      2 = QKV: cols[0,512)->C(q), [512,1024)->kcD@pos, [1024,1536)->vcD@pos (+bias)
//      3 = bias -> split3 planes Csp
//      4 = bias -> fp32 C
// ============================================================================
template<int EPI>
__global__ __launch_bounds__(256, 3) void gemm_sp(
    const u16* __restrict__ Asp, size_t strA,
    const u16* __restrict__ Wsp, size_t strW,
    const float* __restrict__ bias,
    float* __restrict__ C, u16* __restrict__ Csp, size_t strC,
    int N, int Kd, int kcount,
    float* __restrict__ kcD, float* __restrict__ vcD, int pos)
{
    __shared__ u16 sA[12288];   // (p*4 + wband)*1024 + g*512 + lane*8   (24KB)
    __shared__ u16 sB[6144];    // (p*4 + gc)*512 + lane*8               (12KB)
    const int tid = threadIdx.x;
    const int lane = tid & 63, w = tid >> 6;
    const int bm = blockIdx.y * 128, bn = blockIdx.x * 64;
    const int koff = blockIdx.z * kcount;
    const int nt = kcount >> 5;

    // staging decode (constant per thread): A 6 chunks, B 3 chunks, 16B each
    int gA[6], lA[6], gB[3], lB[3];
#pragma unroll
    for (int q = 0; q < 6; ++q) {
        int ca = q * 256 + tid, p = ca >> 9, rem = ca & 511, r = rem >> 2, c = rem & 3;
        gA[q] = p * (int)strA + (bm + r) * Kd + c * 8;
        lA[q] = (p * 4 + (r >> 5)) * 1024 + ((r >> 4) & 1) * 512 + (c * 16 + (r & 15)) * 8;
    }
#pragma unroll
    for (int q = 0; q < 3; ++q) {
        int cc = tid >> 2, c = tid & 3;     // p = q exactly (768 = 3*256)
        gB[q] = q * (int)strW + (bn + cc) * Kd + c * 8;
        lB[q] = (q * 4 + (cc >> 4)) * 512 + (c * 16 + (cc & 15)) * 8;
    }

    f32x4 acc[2][4];
#pragma unroll
    for (int g = 0; g < 2; ++g)
#pragma unroll
        for (int n = 0; n < 4; ++n)
#pragma unroll
            for (int j = 0; j < 4; ++j) acc[g][n][j] = 0.f;

    s16x8 rA[6], rB[3];
#pragma unroll
    for (int q = 0; q < 6; ++q) rA[q] = *(const s16x8*)(Asp + gA[q] + koff);
#pragma unroll
    for (int q = 0; q < 3; ++q) rB[q] = *(const s16x8*)(Wsp + gB[q] + koff);

    for (int t = 0; t < nt; ++t) {
        __syncthreads();                         // previous compute done
#pragma unroll
        for (int q = 0; q < 6; ++q) *(s16x8*)&sA[lA[q]] = rA[q];
#pragma unroll
        for (int q = 0; q < 3; ++q) *(s16x8*)&sB[lB[q]] = rB[q];
        __syncthreads();
        if (t + 1 < nt) {                        // prefetch next K-step into regs
            int o = koff + (t + 1) * 32;
#pragma unroll
            for (int q = 0; q < 6; ++q) rA[q] = *(const s16x8*)(Asp + gA[q] + o);
#pragma unroll
            for (int q = 0; q < 3; ++q) rB[q] = *(const s16x8*)(Wsp + gB[q] + o);
        }
        // fragments and MFMA
        s16x8 a[2][3];
#pragma unroll
        for (int g = 0; g < 2; ++g)
#pragma unroll
            for (int p = 0; p < 3; ++p)
                a[g][p] = *(const s16x8*)&sA[(p * 4 + w) * 1024 + g * 512 + lane * 8];
#pragma unroll
        for (int gc = 0; gc < 4; ++gc) {
            s16x8 b0 = *(const s16x8*)&sB[(0 * 4 + gc) * 512 + lane * 8];
            s16x8 b1 = *(const s16x8*)&sB[(1 * 4 + gc) * 512 + lane * 8];
            s16x8 b2 = *(const s16x8*)&sB[(2 * 4 + gc) * 512 + lane * 8];
#pragma unroll
            for (int g = 0; g < 2; ++g) {
                f32x4 v = acc[g][gc];
                v = __builtin_amdgcn_mfma_f32_16x16x32_bf16(a[g][2], b0, v, 0, 0, 0);
                v = __builtin_amdgcn_mfma_f32_16x16x32_bf16(a[g][0], b2, v, 0, 0, 0);
                v = __builtin_amdgcn_mfma_f32_16x16x32_bf16(a[g][1], b1, v, 0, 0, 0);
                v = __builtin_amdgcn_mfma_f32_16x16x32_bf16(a[g][1], b0, v, 0, 0, 0);
                v = __builtin_amdgcn_mfma_f32_16x16x32_bf16(a[g][0], b1, v, 0, 0, 0);
                v = __builtin_amdgcn_mfma_f32_16x16x32_bf16(a[g][0], b0, v, 0, 0, 0);
                acc[g][gc] = v;
            }
        }
    }

    // epilogue: row=(lane>>4)*4+reg, col=lane&15 [m89]
    const int rbase = bm + w * 32 + (lane >> 4) * 4;
    const int cbase = (lane & 15);
#pragma unroll
    for (int g = 0; g < 2; ++g) {
#pragma unroll
        for (int gc = 0; gc < 4; ++gc) {
            int colg = bn + gc * 16 + cbase;
#pragma unroll
            for (int r = 0; r < 4; ++r) {
                int row = rbase + g * 16 + r;
                float v = acc[g][gc][r];
                if (EPI == 0) {
                    C[(size_t)blockIdx.z * Bb * N + (size_t)row * N + colg] = v;
                } else if (EPI == 1) {
                    v = fmaxf(v + bias[colg], 0.f);
                    u16 s[3]; split3(v, s);
                    size_t o = (size_t)row * N + colg;
                    Csp[o] = s[0]; Csp[strC + o] = s[1]; Csp[2 * strC + o] = s[2];
                } else if (EPI == 2) {
                    v += bias[colg];
                    int seg = colg >> 9, cl = colg & 511;
                    float* dst = (seg == 0) ? (C + (size_t)row * Hdim)
                               : (seg == 1) ? (kcD + ((size_t)pos * Bb + row) * Hdim)
                                            : (vcD + ((size_t)pos * Bb + row) * Hdim);
                    dst[cl] = v;
                } else if (EPI == 3) {
                    v += bias[colg];
                    u16 s[3]; split3(v, s);
                    size_t o = (size_t)row * N + colg;
                    Csp[o] = s[0]; Csp[strC + o] = s[1]; Csp[2 * strC + o] = s[2];
                } else {
                    C[(size_t)row * N + colg] = v + bias[colg];
                }
            }
        }
    }
}

// ---------------- weight split: dst[3 planes][n]
__global__ void split_mat(const float* __restrict__ src, u16* __restrict__ dst, int n)
{
    int i = blockIdx.x * 256 + threadIdx.x;
    if (i < n) {
        u16 s[3]; split3(src[i], s);
        dst[i] = s[0];
        dst[(size_t)n + i] = s[1];
        dst[2 * (size_t)n + i] = s[2];
    }
}

// ---------------- src[b,h] = sum_m emb[(meanings[b,m]+m*K), h] -> split planes
__global__ void src_kernel(const int* __restrict__ meanings,
                           const float* __restrict__ emb, u16* __restrict__ ssp)
{
    int idx = blockIdx.x * 256 + threadIdx.x;
    int b = idx >> 9, h = idx & 511;
    float s = 0.f;
#pragma unroll
    for (int m = 0; m < Mm; ++m) {
        int row = meanings[b * Mm + m] + m * Kk;
        s += emb[(size_t)row * Hdim + h];
    }
    u16 t3[3]; split3(s, t3);
    ssp[idx] = t3[0]; ssp[BH + idx] = t3[1]; ssp[2 * BH + idx] = t3[2];
}

// ---------------- x0 = v2e_w[:,V] + v2e_b + pe(0)
__global__ void init_x(const float* __restrict__ v2e_w, const float* __restrict__ v2e_b,
                       float* __restrict__ x, u16* __restrict__ xsp)
{
    int idx = blockIdx.x * 256 + threadIdx.x;
    int h = idx & 511;
    float s = v2e_w[(size_t)h * V1n + Vv] + v2e_b[h] + ((h & 1) ? 1.f : 0.f);
    x[idx] = s;
    u16 t3[3]; split3(s, t3);
    xsp[idx] = t3[0]; xsp[BH + idx] = t3[1]; xsp[2 * BH + idx] = t3[2];
}

// ---------------- attention vs cache (q,k,v already biased) -> split3 out
__global__ __launch_bounds__(256) void attn_fused(
    const float* __restrict__ qbuf, const float* __restrict__ kc,
    const float* __restrict__ vc, u16* __restrict__ osplit, int step)
{
    __shared__ float qs[Hdim];
    __shared__ float ssm[32];
    __shared__ float wts[32];
    int b = blockIdx.x, tid = threadIdx.x, lane = tid & 63, wv = tid >> 6;
    qs[tid] = qbuf[(size_t)b * Hdim + tid];
    qs[tid + 256] = qbuf[(size_t)b * Hdim + tid + 256];
    __syncthreads();
    const float4* q4 = (const float4*)qs;
    for (int t = wv; t <= step; t += 4) {
        const float4* k4 = (const float4*)(kc + ((size_t)t * Bb + b) * Hdim);
        float4 qa = q4[lane], ka = k4[lane];
        float4 qb = q4[lane + 64], kb = k4[lane + 64];
        float p = qa.x*ka.x + qa.y*ka.y + qa.z*ka.z + qa.w*ka.w
                + qb.x*kb.x + qb.y*kb.y + qb.z*kb.z + qb.w*kb.w;
#pragma unroll
        for (int off = 32; off; off >>= 1) p += __shfl_down(p, off);
        if (!lane) ssm[t] = p * 0.044194173824159216f;   // 1/sqrt(512)
    }
    __syncthreads();
    float m = -1e30f;
    for (int t = 0; t <= step; ++t) m = fmaxf(m, ssm[t]);
    float den = 0.f;
    for (int t = 0; t <= step; ++t) den += expf(ssm[t] - m);
    if (tid <= step) wts[tid] = expf(ssm[tid] - m) / den;
    __syncthreads();
#pragma unroll
    for (int c0 = 0; c0 < 2; ++c0) {
        int h = tid + c0 * 256;
        float a2 = 0.f;
        for (int t = 0; t <= step; ++t)
            a2 += wts[t] * vc[((size_t)t * Bb + b) * Hdim + h];
        u16 t3[3]; split3(a2, t3);
        size_t o = (size_t)b * Hdim + h;
        osplit[o] = t3[0]; osplit[BH + o] = t3[1]; osplit[2 * BH + o] = t3[2];
    }
}

// ---------------- row LN stats (256 thr, 512 elems)
__device__ __forceinline__ float2 rowstats(float v0, float v1, float* sh)
{
    __syncthreads();
    float s = v0 + v1, s2 = v0 * v0 + v1 * v1;
    int lane = threadIdx.x & 63, wv = threadIdx.x >> 6;
#pragma unroll
    for (int off = 32; off; off >>= 1) {
        s += __shfl_down(s, off);
        s2 += __shfl_down(s2, off);
    }
    if (!lane) { sh[wv] = s; sh[wv + 4] = s2; }
    __syncthreads();
    float S = sh[0] + sh[1] + sh[2] + sh[3];
    float S2 = sh[4] + sh[5] + sh[6] + sh[7];
    float mean = S * (1.f / Hdim);
    float var = S2 * (1.f / Hdim) - mean * mean;
    return make_float2(mean, rsqrtf(var + 1e-5f));
}

// ---------------- x = LN2( LN1(x + Σ4 P + ob)*g0+b0 + cross )*g1+b1 ; emit splits
__global__ __launch_bounds__(256) void ln12(
    float* __restrict__ x, const float* __restrict__ P, const float* __restrict__ ob,
    const float* __restrict__ cross,
    const float* __restrict__ g0, const float* __restrict__ b0,
    const float* __restrict__ g1, const float* __restrict__ b1,
    u16* __restrict__ xsp)
{
    __shared__ float sh[8];
    size_t base = (size_t)blockIdx.x * Hdim;
    int tid = threadIdx.x;
    float v0 = x[base + tid] + ob[tid];
    float v1 = x[base + tid + 256] + ob[tid + 256];
#pragma unroll
    for (int z = 0; z < 4; ++z) {
        v0 += P[z * BH + base + tid];
        v1 += P[z * BH + base + tid + 256];
    }
    float2 st = rowstats(v0, v1, sh);
    float y0 = (v0 - st.x) * st.y * g0[tid] + b0[tid] + cross[base + tid];
    float y1 = (v1 - st.x) * st.y * g0[tid + 256] + b0[tid + 256] + cross[base + tid + 256];
    float2 s2 = rowstats(y0, y1, sh);
    float o0 = (y0 - s2.x) * s2.y * g1[tid] + b1[tid];
    float o1 = (y1 - s2.x) * s2.y * g1[tid + 256] + b1[tid + 256];
    x[base + tid] = o0; x[base + tid + 256] = o1;
    u16 t3[3];
    split3(o0, t3); xsp[base+tid]=t3[0]; xsp[BH+base+tid]=t3[1]; xsp[2*BH+base+tid]=t3[2];
    split3(o1, t3); xsp[base+tid+256]=t3[0]; xsp[BH+base+tid+256]=t3[1]; xsp[2*BH+base+tid+256]=t3[2];
}

// ---------------- x = LN(x + Σ4 P + fb)*g+b ; emit splits
__global__ __launch_bounds__(256) void ln3(
    float* __restrict__ x, const float* __restrict__ P, const float* __restrict__ fb,
    const float* __restrict__ g, const float* __restrict__ bbv, u16* __restrict__ xsp)
{
    __shared__ float sh[8];
    size_t base = (size_t)blockIdx.x * Hdim;
    int tid = threadIdx.x;
    float v0 = x[base + tid] + fb[tid];
    float v1 = x[base + tid + 256] + fb[tid + 256];
#pragma unroll
    for (int z = 0; z < 4; ++z) {
        v0 += P[z * BH + base + tid];
        v1 += P[z * BH + base + tid + 256];
    }
    float2 st = rowstats(v0, v1, sh);
    float o0 = (v0 - st.x) * st.y * g[tid] + bbv[tid];
    float o1 = (v1 - st.x) * st.y * g[tid + 256] + bbv[tid + 256];
    x[base + tid] = o0; x[base + tid + 256] = o1;
    u16 t3[3];
    split3(o0, t3); xsp[base+tid]=t3[0]; xsp[BH+base+tid]=t3[1]; xsp[2*BH+base+tid]=t3[2];
    split3(o1, t3); xsp[base+tid+256]=t3[0]; xsp[BH+base+tid+256]=t3[1]; xsp[2*BH+base+tid+256]=t3[2];
}

// ---------------- logits -> out ; probs = softmax ; x = probs@v2e^T + b + pe(next)
__global__ __launch_bounds__(256) void finish_step(
    const float* __restrict__ e2v_w, const float* __restrict__ e2v_b,
    const float* __restrict__ v2e_w, const float* __restrict__ v2e_b,
    float* __restrict__ out_logits, float* __restrict__ x, u16* __restrict__ xsp,
    int pos_next)
{
    __shared__ float xs[Hdim];
    __shared__ float ls[104];
    int b = blockIdx.x, tid = threadIdx.x, lane = tid & 63, wv = tid >> 6;
    xs[tid] = x[(size_t)b * Hdim + tid];
    xs[tid + 256] = x[(size_t)b * Hdim + tid + 256];
    __syncthreads();
    const float4* x4 = (const float4*)xs;
    for (int v = wv; v < V1n; v += 4) {
        const float4* w4 = (const float4*)(e2v_w + (size_t)v * Hdim);
        float4 xa = x4[lane], wa = w4[lane];
        float4 xb = x4[lane + 64], wb = w4[lane + 64];
        float p = xa.x*wa.x + xa.y*wa.y + xa.z*wa.z + xa.w*wa.w
                + xb.x*wb.x + xb.y*wb.y + xb.z*wb.z + xb.w*wb.w;
#pragma unroll
        for (int off = 32; off; off >>= 1) p += __shfl_down(p, off);
        if (!lane) ls[v] = p + e2v_b[v];
    }
    __syncthreads();
    if (tid < V1n) out_logits[(size_t)b * V1n + tid] = ls[tid];
    __syncthreads();
    if (wv == 0) {
        float a0 = (lane < V1n) ? ls[lane] : -1e30f;
        float a1 = (lane + 64 < V1n) ? ls[lane + 64] : -1e30f;
        float mm = fmaxf(a0, a1);
#pragma unroll
        for (int off = 32; off; off >>= 1) mm = fmaxf(mm, __shfl_xor(mm, off));
        float e0 = (lane < V1n) ? expf(a0 - mm) : 0.f;
        float e1 = (lane + 64 < V1n) ? expf(a1 - mm) : 0.f;
        float ssum = e0 + e1;
#pragma unroll
        for (int off = 32; off; off >>= 1) ssum += __shfl_xor(ssum, off);
        float inv = 1.f / ssum;
        if (lane < V1n) ls[lane] = e0 * inv;
        if (lane + 64 < V1n) ls[lane + 64] = e1 * inv;
    }
    __syncthreads();
    for (int h = tid; h < Hdim; h += 256) {
        const float* wr = v2e_w + (size_t)h * V1n;
        float s = v2e_b[h];
        for (int v = 0; v < V1n; ++v) s += ls[v] * wr[v];
        int j2 = h & ~1;
        float div = expf(-(float)j2 * (logf(10000.f) / (float)Hdim));
        float ang = (float)pos_next * div;
        s += (h & 1) ? cosf(ang) : sinf(ang);
        x[(size_t)b * Hdim + h] = s;
        u16 t3[3]; split3(s, t3);
        size_t idx = (size_t)b * Hdim + h;
        xsp[idx] = t3[0]; xsp[BH + idx] = t3[1]; xsp[2 * BH + idx] = t3[2];
    }
}

extern "C" void kernel_launch(void* const* d_in, const int* in_sizes, int n_in,
                              void* d_out, int out_size, void* d_ws, size_t ws_size,
                              hipStream_t stream)
{
    const int*   meanings = (const int*)  d_in[0];
    const float* emb      = (const float*)d_in[1];
    const float* v2e_w    = (const float*)d_in[2];
    const float* v2e_b    = (const float*)d_in[3];
    const float* e2v_w    = (const float*)d_in[4];
    const float* e2v_b    = (const float*)d_in[5];
    const float* sa_in_w  = (const float*)d_in[6];
    const float* sa_in_b  = (const float*)d_in[7];
    const float* sa_out_w = (const float*)d_in[8];
    const float* sa_out_b = (const float*)d_in[9];
    const float* ca_in_w  = (const float*)d_in[10];
    const float* ca_in_b  = (const float*)d_in[11];
    const float* ca_out_w = (const float*)d_in[12];
    const float* ca_out_b = (const float*)d_in[13];
    const float* ff1_w    = (const float*)d_in[14];
    const float* ff1_b    = (const float*)d_in[15];
    const float* ff2_w    = (const float*)d_in[16];
    const float* ff2_b    = (const float*)d_in[17];
    const float* ln_g     = (const float*)d_in[18];
    const float* ln_b     = (const float*)d_in[19];
    float* out = (float*)d_out;

    // ---- ws carve-out (total ~238 MB)
    char* wsb = (char*)d_ws;
    auto alloc = [&](size_t bytes) {
        char* p = wsb; wsb += (bytes + 255) & ~(size_t)255; return p;
    };
    const int nsain = 1536 * 512, nsaout = 512 * 512, nff1 = 2048 * 512,
              nff2 = 512 * 2048, nca = 512 * 512;
    u16 *wsp_sa_in[2], *wsp_sa_out[2], *wsp_ff1[2], *wsp_ff2[2];
    for (int l = 0; l < 2; ++l) wsp_sa_in[l]  = (u16*)alloc((size_t)3 * nsain * 2);
    for (int l = 0; l < 2; ++l) wsp_sa_out[l] = (u16*)alloc((size_t)3 * nsaout * 2);
    for (int l = 0; l < 2; ++l) wsp_ff1[l]    = (u16*)alloc((size_t)3 * nff1 * 2);
    for (int l = 0; l < 2; ++l) wsp_ff2[l]    = (u16*)alloc((size_t)3 * nff2 * 2);
    float* x     = (float*)alloc(BH * 4);                    // 2.10 MB
    u16*   xsp   = (u16*)  alloc(3 * BH * 2);                // 3.15 MB (also attn-out)
    float* cross = (float*)alloc(2 * BH * 4);                // 4.19 MB
    float* qbuf  = (float*)alloc(BH * 4);                    // 2.10 MB
    float* Pbuf  = (float*)alloc(4 * BH * 4);                // 8.39 MB split-K partials
    u16*   h1sp  = (u16*)  alloc(3 * (size_t)Bb * DFFn * 2); // 12.58 MB
    float* kc    = (float*)alloc((size_t)Ln * Tt * BH * 4);  // 83.89 MB
    float* vc    = (float*)alloc((size_t)Ln * Tt * BH * 4);  // 83.89 MB
    // setup-only aliases
    u16* ssp    = h1sp;                          // 3*BH u16 src splits
    u16* wspc_v = (u16*)Pbuf;                    // 3*nca ca V-weight splits
    u16* wspc_o = wspc_v + (size_t)3 * nca;      // 3*nca ca out-weight splits
    u16* vssp   = wspc_o + (size_t)3 * nca;      // 3*BH v-src splits

    // ---- 1) split persistent weights into 3 bf16 planes
    const float* srcs[8] = { sa_in_w, sa_in_w + nsain, sa_out_w, sa_out_w + nsaout,
                             ff1_w, ff1_w + nff1, ff2_w, ff2_w + nff2 };
    u16* dsts[8] = { wsp_sa_in[0], wsp_sa_in[1], wsp_sa_out[0], wsp_sa_out[1],
                     wsp_ff1[0], wsp_ff1[1], wsp_ff2[0], wsp_ff2[1] };
    int ns[8] = { nsain, nsain, nsaout, nsaout, nff1, nff1, nff2, nff2 };
    for (int i = 0; i < 8; ++i)
        split_mat<<<ns[i] / 256, 256, 0, stream>>>(srcs[i], dsts[i], ns[i]);

    // ---- 2) setup: src embedding + per-layer cross-attn constant (S=1 shortcut)
    src_kernel<<<BH / 256, 256, 0, stream>>>(meanings, emb, ssp);
    for (int l = 0; l < Ln; ++l) {
        split_mat<<<nca / 256, 256, 0, stream>>>(
            ca_in_w + (size_t)l * 3 * Hdim * Hdim + (size_t)2 * Hdim * Hdim, wspc_v, nca);
        split_mat<<<nca / 256, 256, 0, stream>>>(
            ca_out_w + (size_t)l * Hdim * Hdim, wspc_o, nca);
        gemm_sp<3><<<dim3(8, 8, 1), 256, 0, stream>>>(
            ssp, BH, wspc_v, (size_t)nca, ca_in_b + l * 1536 + 1024,
            nullptr, vssp, BH, 512, 512, 512, nullptr, nullptr, 0);
        gemm_sp<4><<<dim3(8, 8, 1), 256, 0, stream>>>(
            vssp, BH, wspc_o, (size_t)nca, ca_out_b + l * 512,
            cross + (size_t)l * BH, nullptr, 0, 512, 512, 512, nullptr, nullptr, 0);
    }
    init_x<<<BH / 256, 256, 0, stream>>>(v2e_w, v2e_b, x, xsp);

    // ---- 3) autoregressive loop (incremental decode, KV cache)
    for (int i = 0; i < Tt; ++i) {
        for (int l = 0; l < Ln; ++l) {
            float* kcl = kc + (size_t)l * Tt * BH;
            float* vcl = vc + (size_t)l * Tt * BH;
            // QKV: N=1536, no split-K, epilogue scatters q / kcache / vcache (+bias)
            gemm_sp<2><<<dim3(24, 8, 1), 256, 0, stream>>>(
                xsp, BH, wsp_sa_in[l], (size_t)nsain, sa_in_b + l * 1536,
                qbuf, nullptr, 0, 1536, 512, 512, kcl, vcl, i);
            attn_fused<<<Bb, 256, 0, stream>>>(qbuf, kcl, vcl, xsp, i);
            // out-proj: N=512, splitK4
            gemm_sp<0><<<dim3(8, 8, 4), 256, 0, stream>>>(
                xsp, BH, wsp_sa_out[l], (size_t)nsaout, nullptr,
                Pbuf, nullptr, 0, 512, 512, 128, nullptr, nullptr, 0);
            ln12<<<Bb, 256, 0, stream>>>(x, Pbuf, sa_out_b + l * 512,
                cross + (size_t)l * BH,
                ln_g + (size_t)(l * 3 + 0) * Hdim, ln_b + (size_t)(l * 3 + 0) * Hdim,
                ln_g + (size_t)(l * 3 + 1) * Hdim, ln_b + (size_t)(l * 3 + 1) * Hdim,
                xsp);
            // FF1: N=2048, no split-K, epilogue relu+bias+split3 -> h1sp
            gemm_sp<1><<<dim3(32, 8, 1), 256, 0, stream>>>(
                xsp, BH, wsp_ff1[l], (size_t)nff1, ff1_b + l * 2048,
                nullptr, h1sp, (size_t)Bb * DFFn, 2048, 512, 512, nullptr, nullptr, 0);
            // FF2: N=512, K=2048, splitK4
            gemm_sp<0><<<dim3(8, 8, 4), 256, 0, stream>>>(
                h1sp, (size_t)Bb * DFFn, wsp_ff2[l], (size_t)nff2, nullptr,
                Pbuf, nullptr, 0, 512, 2048, 512, nullptr, nullptr, 0);
            ln3<<<Bb, 256, 0, stream>>>(x, Pbuf, ff2_b + l * 512,
                ln_g + (size_t)(l * 3 + 2) * Hdim, ln_b + (size_t)(l * 3 + 2) * Hdim,
                xsp);
        }
        finish_step<<<Bb, 256, 0, stream>>>(
            e2v_w, e2v_b, v2e_w, v2e_b,
            out + (size_t)i * Bb * V1n, x, xsp, i + 1);
    }
}